// Round 5
// baseline (881.054 us; speedup 1.0000x reference)
//
#include <hip/hip_runtime.h>
#include <hip/hip_bf16.h>

typedef __bf16 bf16_t;
typedef __bf16 bf16x8 __attribute__((ext_vector_type(8)));
typedef float  f32x4  __attribute__((ext_vector_type(4)));

#define D1   1024
#define D3   3072
#define NTOK 32768
#define NH   16

// async global->LDS, 16B per lane. gptr per-lane, lptr wave-uniform.
__device__ __forceinline__ void gl16(const void* g, void* l) {
  __builtin_amdgcn_global_load_lds(
      (__attribute__((address_space(1))) void*)(void*)g,
      (__attribute__((address_space(3))) void*)l, 16, 0, 0);
}

// ---------------------------------------------------------------------------
// k0c: x fp32 -> bf16 (8 elems/thread)
__global__ __launch_bounds__(256) void k0_convert(
    const float* __restrict__ x, bf16_t* __restrict__ xb)
{
  const size_t i = ((size_t)blockIdx.x * 256 + threadIdx.x) * 8;
  const float4 v0 = *reinterpret_cast<const float4*>(&x[i]);
  const float4 v1 = *reinterpret_cast<const float4*>(&x[i + 4]);
  bf16x8 o;
  o[0] = (bf16_t)v0.x; o[1] = (bf16_t)v0.y; o[2] = (bf16_t)v0.z; o[3] = (bf16_t)v0.w;
  o[4] = (bf16_t)v1.x; o[5] = (bf16_t)v1.y; o[6] = (bf16_t)v1.z; o[7] = (bf16_t)v1.w;
  *reinterpret_cast<bf16x8*>(&xb[i]) = o;
}

// ---------------------------------------------------------------------------
// k0: Wt[n][k] = (bf16) W[k][n]
__global__ __launch_bounds__(256) void k0_transpose(
    const float* __restrict__ W, bf16_t* __restrict__ Wt, int K, int N)
{
  __shared__ float tile[32][33];
  const int k0 = blockIdx.x * 32, n0 = blockIdx.y * 32;
  const int tx = threadIdx.x & 31, ty = threadIdx.x >> 5;
#pragma unroll
  for (int i = 0; i < 4; ++i)
    tile[ty + i * 8][tx] = W[(size_t)(k0 + ty + i * 8) * N + n0 + tx];
  __syncthreads();
#pragma unroll
  for (int i = 0; i < 4; ++i)
    Wt[(size_t)(n0 + ty + i * 8) * K + k0 + tx] = (bf16_t)tile[tx][ty + i * 8];
}

// ---------------------------------------------------------------------------
// k1: fused qkv-GEMM + block attention.  1D grid 4096 (XCD-swizzled, h-minor).
// BM=128 x BN=192 (q|k|v of one head), BK=64; waves 2x4, each 64x48.
// Staging: global_load_lds(16B), LINEAR LDS dest, PRE-SWIZZLED global source
// (rule #21); fragment reads XOR (row&7)<<4 into the k-byte-offset -> 2-way.
__global__ __launch_bounds__(512, 6) void k1_qkv_attn(
    const bf16_t* __restrict__ xb, const bf16_t* __restrict__ Wt,
    const float* __restrict__ bqkv, bf16_t* __restrict__ o)
{
  __shared__ __align__(16) unsigned char smem[53248];
  // K-loop: As = smem[0..16384) [128][64] bf16 ; Bs = smem[16384..40960) [192][64]
  bf16_t (*Ss)[200] = reinterpret_cast<bf16_t(*)[200]>(smem);       // epilogue overlay
  float*  Ps        = reinterpret_cast<float*>(smem + 128 * 200 * 2);

  const int tid  = threadIdx.x;
  const int wv   = tid >> 6, lane = tid & 63;
  const int lrow = lane & 15, lkg = lane >> 4;
  const int wr   = wv >> 2, wc = wv & 3;

  // XCD-aware bijective remap (4096 wgs, 8 XCDs, 512/XCD), h-minor so the
  // 16 heads of one m-tile are adjacent within an XCD (share the A-tile).
  const int logical = (blockIdx.x & 7) * 512 + (blockIdx.x >> 3);
  const int h  = logical & 15;
  const int m0 = (logical >> 4) * 128;

  // staging: chunk = 8 rows x 64 cols; lane dest byte = lane*16 (linear).
  // source col is XOR-swizzled so that a swizzled READ returns linear data.
  const int lr  = lane >> 3;                       // row in chunk (0..7)
  const int lcs = ((lane & 7) ^ lr) * 8;           // swizzled col (elements)
  const bf16_t* aS0 = xb + (size_t)(m0 + (wv * 2 + 0) * 8 + lr) * D1 + lcs;
  const bf16_t* aS1 = xb + (size_t)(m0 + (wv * 2 + 1) * 8 + lr) * D1 + lcs;
  char* aD0 = (char*)smem + (wv * 2 + 0) * 1024;
  char* aD1 = (char*)smem + (wv * 2 + 1) * 1024;
  const bf16_t* bS0 = Wt + (size_t)(h * 192 + (wv * 3 + 0) * 8 + lr) * D1 + lcs;
  const bf16_t* bS1 = Wt + (size_t)(h * 192 + (wv * 3 + 1) * 8 + lr) * D1 + lcs;
  const bf16_t* bS2 = Wt + (size_t)(h * 192 + (wv * 3 + 2) * 8 + lr) * D1 + lcs;
  char* bD0 = (char*)smem + 16384 + (wv * 3 + 0) * 1024;
  char* bD1 = (char*)smem + 16384 + (wv * 3 + 1) * 1024;
  char* bD2 = (char*)smem + 16384 + (wv * 3 + 2) * 1024;

  f32x4 acc[4][3];
#pragma unroll
  for (int i = 0; i < 4; ++i)
#pragma unroll
    for (int j = 0; j < 3; ++j) {
      f32x4 z = {0.f, 0.f, 0.f, 0.f};
      acc[i][j] = z;
    }

  const char* As = (const char*)smem;
  const char* Bs = (const char*)smem + 16384;
  const int sw = (lrow & 7) << 4;                  // read-side XOR

  for (int k0 = 0; k0 < D1; k0 += 64) {
    gl16(aS0 + k0, aD0);
    gl16(aS1 + k0, aD1);
    gl16(bS0 + k0, bD0);
    gl16(bS1 + k0, bD1);
    gl16(bS2 + k0, bD2);
    __syncthreads();
#pragma unroll
    for (int kk = 0; kk < 2; ++kk) {
      const int koff = (kk * 64 + lkg * 16) ^ sw;
      bf16x8 a[4];
#pragma unroll
      for (int rf = 0; rf < 4; ++rf)
        a[rf] = *reinterpret_cast<const bf16x8*>(
            As + (wr * 64 + rf * 16 + lrow) * 128 + koff);
#pragma unroll
      for (int cf = 0; cf < 3; ++cf) {
        const bf16x8 b = *reinterpret_cast<const bf16x8*>(
            Bs + (wc * 48 + cf * 16 + lrow) * 128 + koff);
#pragma unroll
        for (int rf = 0; rf < 4; ++rf)
          acc[rf][cf] = __builtin_amdgcn_mfma_f32_16x16x32_bf16(
              a[rf], b, acc[rf][cf], 0, 0, 0);
      }
    }
    __syncthreads();
  }

  // S -> LDS (bf16), + bias.  C/D: col=lane&15, row=(lane>>4)*4+reg
#pragma unroll
  for (int cf = 0; cf < 3; ++cf) {
    const int col = wc * 48 + cf * 16 + lrow;
    const float bias = bqkv[h * 192 + col];
#pragma unroll
    for (int rf = 0; rf < 4; ++rf) {
      const int row = wr * 64 + rf * 16 + lkg * 4;
#pragma unroll
      for (int r = 0; r < 4; ++r)
        Ss[row + r][col] = (bf16_t)(acc[rf][cf][r] + bias);
    }
  }
  __syncthreads();

  // phase A: logits + softmax. tid -> (blk, qi, kj)
  {
    const int blk = tid >> 4, qi = (tid >> 2) & 3, kj = tid & 3;
    float s = 0.f;
#pragma unroll
    for (int c8 = 0; c8 < 8; ++c8) {
      const bf16x8 qv = *reinterpret_cast<const bf16x8*>(&Ss[blk * 4 + qi][c8 * 8]);
      const bf16x8 kv = *reinterpret_cast<const bf16x8*>(&Ss[blk * 4 + kj][64 + c8 * 8]);
#pragma unroll
      for (int u = 0; u < 8; ++u) s += (float)qv[u] * (float)kv[u];
    }
    s *= 0.125f;
    float mx = fmaxf(s, __shfl_xor(s, 1));
    mx = fmaxf(mx, __shfl_xor(mx, 2));
    const float e = __expf(s - mx);
    float sum = e + __shfl_xor(e, 1);
    sum += __shfl_xor(sum, 2);
    Ps[tid] = e / sum;
  }
  __syncthreads();

  // phase B: o = P @ V, bf16 to workspace
  {
    const int row = tid >> 2;
    const int blk = row >> 2, qi = row & 3;
    const int c0 = (tid & 3) * 16;
    const float p0 = Ps[blk * 16 + qi * 4 + 0];
    const float p1 = Ps[blk * 16 + qi * 4 + 1];
    const float p2 = Ps[blk * 16 + qi * 4 + 2];
    const float p3 = Ps[blk * 16 + qi * 4 + 3];
    bf16x8 outv[2];
#pragma unroll
    for (int hf = 0; hf < 2; ++hf) {
      const bf16x8 v0 = *reinterpret_cast<const bf16x8*>(&Ss[blk * 4 + 0][128 + c0 + hf * 8]);
      const bf16x8 v1 = *reinterpret_cast<const bf16x8*>(&Ss[blk * 4 + 1][128 + c0 + hf * 8]);
      const bf16x8 v2 = *reinterpret_cast<const bf16x8*>(&Ss[blk * 4 + 2][128 + c0 + hf * 8]);
      const bf16x8 v3 = *reinterpret_cast<const bf16x8*>(&Ss[blk * 4 + 3][128 + c0 + hf * 8]);
#pragma unroll
      for (int u = 0; u < 8; ++u)
        outv[hf][u] = (bf16_t)(p0 * (float)v0[u] + p1 * (float)v1[u] +
                               p2 * (float)v2[u] + p3 * (float)v3[u]);
    }
    bf16_t* dst = &o[(size_t)(m0 + row) * D1 + h * 64 + c0];
    *reinterpret_cast<bf16x8*>(dst)     = outv[0];
    *reinterpret_cast<bf16x8*>(dst + 8) = outv[1];
  }
}

// ---------------------------------------------------------------------------
// k2: out = o @ W_proj + b_proj.  1D grid 2048 (XCD-swizzled, n-minor).
__global__ __launch_bounds__(256, 3) void k2_proj(
    const bf16_t* __restrict__ o, const bf16_t* __restrict__ Wpt,
    const float* __restrict__ bp, float* __restrict__ out)
{
  __shared__ __align__(16) unsigned char smem2[32768];  // As 16K | Bs 16K

  const int tid  = threadIdx.x;
  const int wv   = tid >> 6, lane = tid & 63;
  const int lrow = lane & 15, lkg = lane >> 4;
  const int wr   = wv >> 1, wc = wv & 1;

  const int logical = (blockIdx.x & 7) * 256 + (blockIdx.x >> 3);
  const int n0 = (logical & 7) * 128;
  const int m0 = (logical >> 3) * 128;

  const int lr  = lane >> 3;
  const int lcs = ((lane & 7) ^ lr) * 8;           // swizzled source col
  const bf16_t* aSrc[4];
  const bf16_t* bSrc[4];
  char *aDst[4], *bDst[4];
#pragma unroll
  for (int i = 0; i < 4; ++i) {
    const int ch = wv * 4 + i;
    aSrc[i] = o   + (size_t)(m0 + ch * 8 + lr) * D1 + lcs;
    bSrc[i] = Wpt + (size_t)(n0 + ch * 8 + lr) * D1 + lcs;
    aDst[i] = (char*)smem2 + ch * 1024;
    bDst[i] = (char*)smem2 + 16384 + ch * 1024;
  }

  f32x4 acc[4][4];
#pragma unroll
  for (int i = 0; i < 4; ++i)
#pragma unroll
    for (int j = 0; j < 4; ++j) {
      f32x4 z = {0.f, 0.f, 0.f, 0.f};
      acc[i][j] = z;
    }

  const char* As = (const char*)smem2;
  const char* Bs = (const char*)smem2 + 16384;
  const int sw = (lrow & 7) << 4;

  for (int k0 = 0; k0 < D1; k0 += 64) {
#pragma unroll
    for (int i = 0; i < 4; ++i) {
      gl16(aSrc[i] + k0, aDst[i]);
      gl16(bSrc[i] + k0, bDst[i]);
    }
    __syncthreads();
#pragma unroll
    for (int kk = 0; kk < 2; ++kk) {
      const int koff = (kk * 64 + lkg * 16) ^ sw;
      bf16x8 a[4], b[4];
#pragma unroll
      for (int rf = 0; rf < 4; ++rf)
        a[rf] = *reinterpret_cast<const bf16x8*>(
            As + (wr * 64 + rf * 16 + lrow) * 128 + koff);
#pragma unroll
      for (int cf = 0; cf < 4; ++cf)
        b[cf] = *reinterpret_cast<const bf16x8*>(
            Bs + (wc * 64 + cf * 16 + lrow) * 128 + koff);
#pragma unroll
      for (int rf = 0; rf < 4; ++rf)
#pragma unroll
        for (int cf = 0; cf < 4; ++cf)
          acc[rf][cf] = __builtin_amdgcn_mfma_f32_16x16x32_bf16(
              a[rf], b[cf], acc[rf][cf], 0, 0, 0);
    }
    __syncthreads();
  }

#pragma unroll
  for (int cf = 0; cf < 4; ++cf) {
    const int col = n0 + wc * 64 + cf * 16 + lrow;
    const float bias = bp[col];
#pragma unroll
    for (int rf = 0; rf < 4; ++rf) {
      const size_t row = (size_t)m0 + wr * 64 + rf * 16 + lkg * 4;
#pragma unroll
      for (int r = 0; r < 4; ++r)
        out[(row + r) * D1 + col] = acc[rf][cf][r] + bias;
    }
  }
}

// ---------------------------------------------------------------------------
extern "C" void kernel_launch(void* const* d_in, const int* in_sizes, int n_in,
                              void* d_out, int out_size, void* d_ws, size_t ws_size,
                              hipStream_t stream)
{
  const float* x    = (const float*)d_in[0];
  const float* Wqkv = (const float*)d_in[1];
  const float* bqkv = (const float*)d_in[2];
  const float* Wp   = (const float*)d_in[3];
  const float* bp   = (const float*)d_in[4];
  float* out        = (float*)d_out;

  bf16_t* xb   = (bf16_t*)d_ws;                       // [32768][1024] bf16
  bf16_t* o_ws = xb   + (size_t)NTOK * D1;            // [32768][1024] bf16
  bf16_t* wtq  = o_ws + (size_t)NTOK * D1;            // [3072][1024]  bf16
  bf16_t* wtp  = wtq  + (size_t)D3 * D1;              // [1024][1024]  bf16

  k0_convert<<<NTOK * D1 / (256 * 8), 256, 0, stream>>>(x, xb);
  k0_transpose<<<dim3(D1 / 32, D3 / 32), 256, 0, stream>>>(Wqkv, wtq, D1, D3);
  k0_transpose<<<dim3(D1 / 32, D1 / 32), 256, 0, stream>>>(Wp,   wtp, D1, D1);
  k1_qkv_attn<<<4096, 512, 0, stream>>>(xb, wtq, bqkv, o_ws);
  k2_proj<<<2048, 256, 0, stream>>>(o_ws, wtp, bp, out);
}

// Round 6
// 524.959 us; speedup vs baseline: 1.6783x; 1.6783x over previous
//
#include <hip/hip_runtime.h>
#include <hip/hip_bf16.h>

typedef __bf16 bf16_t;
typedef __bf16 bf16x8 __attribute__((ext_vector_type(8)));
typedef float  f32x4  __attribute__((ext_vector_type(4)));

#define D1   1024
#define D3   3072
#define NTOK 32768
#define NH   16

// async global->LDS, 16B per lane. gptr per-lane, lptr wave-uniform.
__device__ __forceinline__ void gl16(const void* g, void* l) {
  __builtin_amdgcn_global_load_lds(
      (__attribute__((address_space(1))) void*)(void*)g,
      (__attribute__((address_space(3))) void*)l, 16, 0, 0);
}

// ---------------------------------------------------------------------------
// k0c: x fp32 -> bf16 (8 elems/thread)
__global__ __launch_bounds__(256) void k0_convert(
    const float* __restrict__ x, bf16_t* __restrict__ xb)
{
  const size_t i = ((size_t)blockIdx.x * 256 + threadIdx.x) * 8;
  const float4 v0 = *reinterpret_cast<const float4*>(&x[i]);
  const float4 v1 = *reinterpret_cast<const float4*>(&x[i + 4]);
  bf16x8 o;
  o[0] = (bf16_t)v0.x; o[1] = (bf16_t)v0.y; o[2] = (bf16_t)v0.z; o[3] = (bf16_t)v0.w;
  o[4] = (bf16_t)v1.x; o[5] = (bf16_t)v1.y; o[6] = (bf16_t)v1.z; o[7] = (bf16_t)v1.w;
  *reinterpret_cast<bf16x8*>(&xb[i]) = o;
}

// ---------------------------------------------------------------------------
// k0: Wt[n][k] = (bf16) W[k][n]
__global__ __launch_bounds__(256) void k0_transpose(
    const float* __restrict__ W, bf16_t* __restrict__ Wt, int K, int N)
{
  __shared__ float tile[32][33];
  const int k0 = blockIdx.x * 32, n0 = blockIdx.y * 32;
  const int tx = threadIdx.x & 31, ty = threadIdx.x >> 5;
#pragma unroll
  for (int i = 0; i < 4; ++i)
    tile[ty + i * 8][tx] = W[(size_t)(k0 + ty + i * 8) * N + n0 + tx];
  __syncthreads();
#pragma unroll
  for (int i = 0; i < 4; ++i)
    Wt[(size_t)(n0 + ty + i * 8) * K + k0 + tx] = (bf16_t)tile[tx][ty + i * 8];
}

// ---------------------------------------------------------------------------
// k1: fused qkv-GEMM + block attention.  1D grid 4096 (XCD-swizzled, h-minor).
// BM=128 x BN=192 (q|k|v of one head), BK=64; waves 2x4, each 64x48.
// Staging: global_load_lds(16B), LINEAR LDS dest, PRE-SWIZZLED global source
// (rule #21); fragment reads XOR (row&7)<<4 into the k-byte-offset.
// NOTE launch_bounds (512,4): (512,6) forced VGPR cap 40 -> acc spill to
// scratch (WRITE_SIZE 65MB -> 1.16GB, dur +80%).  Do not raise again.
__global__ __launch_bounds__(512, 4) void k1_qkv_attn(
    const bf16_t* __restrict__ xb, const bf16_t* __restrict__ Wt,
    const float* __restrict__ bqkv, bf16_t* __restrict__ o)
{
  __shared__ __align__(16) unsigned char smem[53248];
  // K-loop: As = smem[0..16384) [128][64] bf16 ; Bs = smem[16384..40960) [192][64]
  bf16_t (*Ss)[200] = reinterpret_cast<bf16_t(*)[200]>(smem);       // epilogue overlay
  float*  Ps        = reinterpret_cast<float*>(smem + 128 * 200 * 2);

  const int tid  = threadIdx.x;
  const int wv   = tid >> 6, lane = tid & 63;
  const int lrow = lane & 15, lkg = lane >> 4;
  const int wr   = wv >> 2, wc = wv & 3;

  // XCD-aware bijective remap (4096 wgs, 8 XCDs, 512/XCD), h-minor so the
  // 16 heads of one m-tile are adjacent within an XCD (share the A-tile).
  const int logical = (blockIdx.x & 7) * 512 + (blockIdx.x >> 3);
  const int h  = logical & 15;
  const int m0 = (logical >> 4) * 128;

  // staging: chunk = 8 rows x 64 cols; lane dest byte = lane*16 (linear).
  // source col is XOR-swizzled so that a swizzled READ returns linear data.
  const int lr  = lane >> 3;                       // row in chunk (0..7)
  const int lcs = ((lane & 7) ^ lr) * 8;           // swizzled col (elements)
  const bf16_t* aS0 = xb + (size_t)(m0 + (wv * 2 + 0) * 8 + lr) * D1 + lcs;
  const bf16_t* aS1 = xb + (size_t)(m0 + (wv * 2 + 1) * 8 + lr) * D1 + lcs;
  char* aD0 = (char*)smem + (wv * 2 + 0) * 1024;
  char* aD1 = (char*)smem + (wv * 2 + 1) * 1024;
  const bf16_t* bS0 = Wt + (size_t)(h * 192 + (wv * 3 + 0) * 8 + lr) * D1 + lcs;
  const bf16_t* bS1 = Wt + (size_t)(h * 192 + (wv * 3 + 1) * 8 + lr) * D1 + lcs;
  const bf16_t* bS2 = Wt + (size_t)(h * 192 + (wv * 3 + 2) * 8 + lr) * D1 + lcs;
  char* bD0 = (char*)smem + 16384 + (wv * 3 + 0) * 1024;
  char* bD1 = (char*)smem + 16384 + (wv * 3 + 1) * 1024;
  char* bD2 = (char*)smem + 16384 + (wv * 3 + 2) * 1024;

  f32x4 acc[4][3];
#pragma unroll
  for (int i = 0; i < 4; ++i)
#pragma unroll
    for (int j = 0; j < 3; ++j) {
      f32x4 z = {0.f, 0.f, 0.f, 0.f};
      acc[i][j] = z;
    }

  const char* As = (const char*)smem;
  const char* Bs = (const char*)smem + 16384;
  const int sw = (lrow & 7) << 4;                  // read-side XOR

  for (int k0 = 0; k0 < D1; k0 += 64) {
    gl16(aS0 + k0, aD0);
    gl16(aS1 + k0, aD1);
    gl16(bS0 + k0, bD0);
    gl16(bS1 + k0, bD1);
    gl16(bS2 + k0, bD2);
    __syncthreads();
#pragma unroll
    for (int kk = 0; kk < 2; ++kk) {
      const int koff = (kk * 64 + lkg * 16) ^ sw;
      bf16x8 a[4];
#pragma unroll
      for (int rf = 0; rf < 4; ++rf)
        a[rf] = *reinterpret_cast<const bf16x8*>(
            As + (wr * 64 + rf * 16 + lrow) * 128 + koff);
#pragma unroll
      for (int cf = 0; cf < 3; ++cf) {
        const bf16x8 b = *reinterpret_cast<const bf16x8*>(
            Bs + (wc * 48 + cf * 16 + lrow) * 128 + koff);
#pragma unroll
        for (int rf = 0; rf < 4; ++rf)
          acc[rf][cf] = __builtin_amdgcn_mfma_f32_16x16x32_bf16(
              a[rf], b, acc[rf][cf], 0, 0, 0);
      }
    }
    __syncthreads();
  }

  // S -> LDS (bf16), + bias.  C/D: col=lane&15, row=(lane>>4)*4+reg
#pragma unroll
  for (int cf = 0; cf < 3; ++cf) {
    const int col = wc * 48 + cf * 16 + lrow;
    const float bias = bqkv[h * 192 + col];
#pragma unroll
    for (int rf = 0; rf < 4; ++rf) {
      const int row = wr * 64 + rf * 16 + lkg * 4;
#pragma unroll
      for (int r = 0; r < 4; ++r)
        Ss[row + r][col] = (bf16_t)(acc[rf][cf][r] + bias);
    }
  }
  __syncthreads();

  // phase A: logits + softmax. tid -> (blk, qi, kj)
  {
    const int blk = tid >> 4, qi = (tid >> 2) & 3, kj = tid & 3;
    float s = 0.f;
#pragma unroll
    for (int c8 = 0; c8 < 8; ++c8) {
      const bf16x8 qv = *reinterpret_cast<const bf16x8*>(&Ss[blk * 4 + qi][c8 * 8]);
      const bf16x8 kv = *reinterpret_cast<const bf16x8*>(&Ss[blk * 4 + kj][64 + c8 * 8]);
#pragma unroll
      for (int u = 0; u < 8; ++u) s += (float)qv[u] * (float)kv[u];
    }
    s *= 0.125f;
    float mx = fmaxf(s, __shfl_xor(s, 1));
    mx = fmaxf(mx, __shfl_xor(mx, 2));
    const float e = __expf(s - mx);
    float sum = e + __shfl_xor(e, 1);
    sum += __shfl_xor(sum, 2);
    Ps[tid] = e / sum;
  }
  __syncthreads();

  // phase B: o = P @ V, bf16 to workspace
  {
    const int row = tid >> 2;
    const int blk = row >> 2, qi = row & 3;
    const int c0 = (tid & 3) * 16;
    const float p0 = Ps[blk * 16 + qi * 4 + 0];
    const float p1 = Ps[blk * 16 + qi * 4 + 1];
    const float p2 = Ps[blk * 16 + qi * 4 + 2];
    const float p3 = Ps[blk * 16 + qi * 4 + 3];
    bf16x8 outv[2];
#pragma unroll
    for (int hf = 0; hf < 2; ++hf) {
      const bf16x8 v0 = *reinterpret_cast<const bf16x8*>(&Ss[blk * 4 + 0][128 + c0 + hf * 8]);
      const bf16x8 v1 = *reinterpret_cast<const bf16x8*>(&Ss[blk * 4 + 1][128 + c0 + hf * 8]);
      const bf16x8 v2 = *reinterpret_cast<const bf16x8*>(&Ss[blk * 4 + 2][128 + c0 + hf * 8]);
      const bf16x8 v3 = *reinterpret_cast<const bf16x8*>(&Ss[blk * 4 + 3][128 + c0 + hf * 8]);
#pragma unroll
      for (int u = 0; u < 8; ++u)
        outv[hf][u] = (bf16_t)(p0 * (float)v0[u] + p1 * (float)v1[u] +
                               p2 * (float)v2[u] + p3 * (float)v3[u]);
    }
    bf16_t* dst = &o[(size_t)(m0 + row) * D1 + h * 64 + c0];
    *reinterpret_cast<bf16x8*>(dst)     = outv[0];
    *reinterpret_cast<bf16x8*>(dst + 8) = outv[1];
  }
}

// ---------------------------------------------------------------------------
// k2: out = o @ W_proj + b_proj.  1D grid 2048 (XCD-swizzled, n-minor).
__global__ __launch_bounds__(256, 2) void k2_proj(
    const bf16_t* __restrict__ o, const bf16_t* __restrict__ Wpt,
    const float* __restrict__ bp, float* __restrict__ out)
{
  __shared__ __align__(16) unsigned char smem2[32768];  // As 16K | Bs 16K

  const int tid  = threadIdx.x;
  const int wv   = tid >> 6, lane = tid & 63;
  const int lrow = lane & 15, lkg = lane >> 4;
  const int wr   = wv >> 1, wc = wv & 1;

  const int logical = (blockIdx.x & 7) * 256 + (blockIdx.x >> 3);
  const int n0 = (logical & 7) * 128;
  const int m0 = (logical >> 3) * 128;

  const int lr  = lane >> 3;
  const int lcs = ((lane & 7) ^ lr) * 8;           // swizzled source col
  const bf16_t* aSrc[4];
  const bf16_t* bSrc[4];
  char *aDst[4], *bDst[4];
#pragma unroll
  for (int i = 0; i < 4; ++i) {
    const int ch = wv * 4 + i;
    aSrc[i] = o   + (size_t)(m0 + ch * 8 + lr) * D1 + lcs;
    bSrc[i] = Wpt + (size_t)(n0 + ch * 8 + lr) * D1 + lcs;
    aDst[i] = (char*)smem2 + ch * 1024;
    bDst[i] = (char*)smem2 + 16384 + ch * 1024;
  }

  f32x4 acc[4][4];
#pragma unroll
  for (int i = 0; i < 4; ++i)
#pragma unroll
    for (int j = 0; j < 4; ++j) {
      f32x4 z = {0.f, 0.f, 0.f, 0.f};
      acc[i][j] = z;
    }

  const char* As = (const char*)smem2;
  const char* Bs = (const char*)smem2 + 16384;
  const int sw = (lrow & 7) << 4;

  for (int k0 = 0; k0 < D1; k0 += 64) {
#pragma unroll
    for (int i = 0; i < 4; ++i) {
      gl16(aSrc[i] + k0, aDst[i]);
      gl16(bSrc[i] + k0, bDst[i]);
    }
    __syncthreads();
#pragma unroll
    for (int kk = 0; kk < 2; ++kk) {
      const int koff = (kk * 64 + lkg * 16) ^ sw;
      bf16x8 a[4], b[4];
#pragma unroll
      for (int rf = 0; rf < 4; ++rf)
        a[rf] = *reinterpret_cast<const bf16x8*>(
            As + (wr * 64 + rf * 16 + lrow) * 128 + koff);
#pragma unroll
      for (int cf = 0; cf < 4; ++cf)
        b[cf] = *reinterpret_cast<const bf16x8*>(
            Bs + (wc * 64 + cf * 16 + lrow) * 128 + koff);
#pragma unroll
      for (int rf = 0; rf < 4; ++rf)
#pragma unroll
        for (int cf = 0; cf < 4; ++cf)
          acc[rf][cf] = __builtin_amdgcn_mfma_f32_16x16x32_bf16(
              a[rf], b[cf], acc[rf][cf], 0, 0, 0);
    }
    __syncthreads();
  }

#pragma unroll
  for (int cf = 0; cf < 4; ++cf) {
    const int col = n0 + wc * 64 + cf * 16 + lrow;
    const float bias = bp[col];
#pragma unroll
    for (int rf = 0; rf < 4; ++rf) {
      const size_t row = (size_t)m0 + wr * 64 + rf * 16 + lkg * 4;
#pragma unroll
      for (int r = 0; r < 4; ++r)
        out[(row + r) * D1 + col] = acc[rf][cf][r] + bias;
    }
  }
}

// ---------------------------------------------------------------------------
extern "C" void kernel_launch(void* const* d_in, const int* in_sizes, int n_in,
                              void* d_out, int out_size, void* d_ws, size_t ws_size,
                              hipStream_t stream)
{
  const float* x    = (const float*)d_in[0];
  const float* Wqkv = (const float*)d_in[1];
  const float* bqkv = (const float*)d_in[2];
  const float* Wp   = (const float*)d_in[3];
  const float* bp   = (const float*)d_in[4];
  float* out        = (float*)d_out;

  bf16_t* xb   = (bf16_t*)d_ws;                       // [32768][1024] bf16
  bf16_t* o_ws = xb   + (size_t)NTOK * D1;            // [32768][1024] bf16
  bf16_t* wtq  = o_ws + (size_t)NTOK * D1;            // [3072][1024]  bf16
  bf16_t* wtp  = wtq  + (size_t)D3 * D1;              // [1024][1024]  bf16

  k0_convert<<<NTOK * D1 / (256 * 8), 256, 0, stream>>>(x, xb);
  k0_transpose<<<dim3(D1 / 32, D3 / 32), 256, 0, stream>>>(Wqkv, wtq, D1, D3);
  k0_transpose<<<dim3(D1 / 32, D1 / 32), 256, 0, stream>>>(Wp,   wtp, D1, D1);
  k1_qkv_attn<<<4096, 512, 0, stream>>>(xb, wtq, bqkv, o_ws);
  k2_proj<<<2048, 256, 0, stream>>>(o_ws, wtp, bp, out);
}